// Round 1
// 480.951 us; speedup vs baseline: 1.0488x; 1.0488x over previous
//
#include <hip/hip_runtime.h>
#include <stdint.h>

// Problem constants (from reference)
#define N_VIEWS 5
#define B_ 8
#define C_ 15
#define CP_ 16               // channel-padded: 16 x fp8 = 16B per pixel
#define H_ 256
#define W_ 480
#define NBINS 128000          // 80*80*20
#define HW_ (H_ * W_)
#define CUBES_ELEMS (B_ * C_ * NBINS)
#define NB_ (N_VIEWS * B_)    // 40 images

typedef float v2f __attribute__((ext_vector_type(2)));

// ---------------------------------------------------------------------------
// Kernel 1: transpose+quantize (N,B,C,H,W) f32 -> (N,B,H,W,16) fp8 e4m3 (OCP)
// Coalesced reads per channel; each lane writes one 16B pixel record.
// Total ws: 40 * 122880 * 16 B = 78.6 MB. At the HBM read floor (~983 MB f32).
// ---------------------------------------------------------------------------
__global__ __launch_bounds__(256) void transpose_fp8_kernel(
    const float* __restrict__ hm, uint32_t* __restrict__ tp)
{
    const int idx = blockIdx.x * 256 + threadIdx.x;   // pixel within image
    const int cb  = blockIdx.y;                       // 0..39
    if (idx >= HW_) return;
    const float* src = hm + (size_t)cb * C_ * HW_ + idx;
    float v[CP_];
#pragma unroll
    for (int c = 0; c < C_; ++c) v[c] = src[(size_t)c * HW_];
    v[15] = 0.0f;
    uint32_t w[4];
#pragma unroll
    for (int j = 0; j < 4; ++j) {
        int r = 0;
        r = __builtin_amdgcn_cvt_pk_fp8_f32(v[4*j + 0], v[4*j + 1], r, false); // bytes 1:0
        r = __builtin_amdgcn_cvt_pk_fp8_f32(v[4*j + 2], v[4*j + 3], r, true);  // bytes 3:2
        w[j] = (uint32_t)r;
    }
    uint4* dst = (uint4*)(tp + ((size_t)cb * HW_ + (size_t)idx) * 4);
    *dst = make_uint4(w[0], w[1], w[2], w[3]);
}

// ---------------------------------------------------------------------------
// Shared projection math — fully branchless. For out-of-bounds views all four
// weights are 0 and offsets are pinned to record 0 (one cached line).
// No NaN hazard: cameras sit outside the grid (zcm > 0 always), so u,v are
// finite; weights stay finite and the *inb multiply makes them exactly 0.
// ---------------------------------------------------------------------------
struct Proj { int o00, o10, o01, o11; float w00, w10, w01, w11, inb; };

__device__ __forceinline__ Proj project_one(
    int cb, float gx, float gy, float gz,
    const float* __restrict__ R, const float* __restrict__ T,
    const float* __restrict__ f, const float* __restrict__ ccam,
    const float* __restrict__ trans, const float* __restrict__ wh)
{
    Proj r;
    const float* Rn = R + cb * 9;
    const float px = gx - T[cb * 3 + 0];
    const float py = gy - T[cb * 3 + 1];
    const float pz = gz - T[cb * 3 + 2];
    const float xcm = Rn[0] * px + Rn[1] * py + Rn[2] * pz;
    const float ycm = Rn[3] * px + Rn[4] * py + Rn[5] * pz;
    const float zcm = Rn[6] * px + Rn[7] * py + Rn[8] * pz;
    const float u = f[cb * 2 + 0] * (xcm / zcm) + ccam[cb * 2 + 0];
    const float v = f[cb * 2 + 1] * (ycm / zcm) + ccam[cb * 2 + 1];
    const float w0 = wh[cb * 2 + 0], w1 = wh[cb * 2 + 1];
    const bool inb = (u >= 0.0f) & (u < w0) & (v >= 0.0f) & (v < w1);
    const float inbf = inb ? 1.0f : 0.0f;
    const float mx = fmaxf(w0, w1);
    const float uu = fminf(fmaxf(u, -1.0f), mx);
    const float vv = fminf(fmaxf(v, -1.0f), mx);
    const float* tr = trans + cb * 6;
    const float tx = (tr[0] * uu + tr[1] * vv + tr[2]) * 0.5f;
    const float ty = (tr[3] * uu + tr[4] * vv + tr[5]) * 0.5f;
    const float sgx = fminf(fmaxf(tx / 479.0f * 2.0f - 1.0f, -1.1f), 1.1f);
    const float sgy = fminf(fmaxf(ty / 255.0f * 2.0f - 1.0f, -1.1f), 1.1f);
    const float ixf = (sgx + 1.0f) * 0.5f * 479.0f;
    const float iyf = (sgy + 1.0f) * 0.5f * 255.0f;
    const float x0 = floorf(ixf), y0 = floorf(iyf);
    const float x1 = x0 + 1.0f, y1 = y0 + 1.0f;
    const float wx1 = ixf - x0, wy1 = iyf - y0;
    const float wx0 = 1.0f - wx1, wy0 = 1.0f - wy1;
    const float v00 = (x0 >= 0.0f && y0 >= 0.0f) ? inbf : 0.0f;
    const float v10 = (x1 <= 479.0f && y0 >= 0.0f) ? inbf : 0.0f;
    const float v01 = (x0 >= 0.0f && y1 <= 255.0f) ? inbf : 0.0f;
    const float v11 = (x1 <= 479.0f && y1 <= 255.0f) ? inbf : 0.0f;
    r.w00 = wx0 * wy0 * v00; r.w10 = wx1 * wy0 * v10;
    r.w01 = wx0 * wy1 * v01; r.w11 = wx1 * wy1 * v11;
    const int xi0 = min(max((int)x0, 0), W_ - 1);
    const int yi0 = min(max((int)y0, 0), H_ - 1);
    const int xi1 = min(max((int)x1, 0), W_ - 1);
    const int yi1 = min(max((int)y1, 0), H_ - 1);
    const int o00 = yi0 * W_ + xi0, o10 = yi0 * W_ + xi1;
    const int o01 = yi1 * W_ + xi0, o11 = yi1 * W_ + xi1;
    // OOB views: pin all four gathers to record 0 (single hot line in L1).
    r.o00 = inb ? o00 : 0; r.o10 = inb ? o10 : 0;
    r.o01 = inb ? o01 : 0; r.o11 = inb ? o11 : 0;
    r.inb = inbf;
    return r;
}

__device__ __forceinline__ void decode_grid(int p, int b, const float* __restrict__ gc,
                                            float& gx, float& gy, float& gz)
{
    const int ixg = p / 1600;
    const int rem = p - ixg * 1600;
    const int iyg = rem / 20;
    const int izg = rem - iyg * 20;
    gx = (float)(-4000.0 + ixg * (8000.0 / 79.0)) + gc[b * 3 + 0];
    gy = (float)(-4000.0 + iyg * (8000.0 / 79.0)) + gc[b * 3 + 1];
    gz = (float)(-1000.0 + izg * (2000.0 / 19.0)) + gc[b * 3 + 2];
}

// decode one 16B pixel record (16 fp8) and FMA with weight into acc[16]
__device__ __forceinline__ void acc_pixel(float* acc, uint4 q, float wgt)
{
    const uint32_t u[4] = { q.x, q.y, q.z, q.w };
#pragma unroll
    for (int j = 0; j < 4; ++j) {
        v2f lo = __builtin_amdgcn_cvt_pk_f32_fp8(u[j], false);
        v2f hi = __builtin_amdgcn_cvt_pk_f32_fp8(u[j], true);
        acc[4*j + 0] += wgt * lo.x;
        acc[4*j + 1] += wgt * lo.y;
        acc[4*j + 2] += wgt * hi.x;
        acc[4*j + 3] += wgt * hi.y;
    }
}

// ---------------------------------------------------------------------------
// Kernel 2: projection gathering fp8 channel-last pixels (16B per corner).
// XCD-affinity swizzle: grid is flat 4000 blocks; b = bid & 7 so each of the
// 8 XCDs (round-robin workgroup placement) serves exactly one batch b.
// Per-XCD gather working set = that b's 5 images (9.6 MB), instantaneous
// sweep footprint ~3 MB -> fits the 4 MB per-XCD L2.
// All 20 gathers issued branchlessly before accumulation (deep MLP).
// ---------------------------------------------------------------------------
__global__ __launch_bounds__(256) void project_kernel_fp8(
    const uint32_t* __restrict__ tp,  // (N,B,H,W,16) fp8
    const float* __restrict__ R, const float* __restrict__ T,
    const float* __restrict__ f, const float* __restrict__ ccam,
    const float* __restrict__ trans, const float* __restrict__ wh,
    const float* __restrict__ gc,
    float* __restrict__ out)
{
    const int bid = blockIdx.x;            // 0..3999
    const int b   = bid & 7;               // XCD affinity: one b per XCD
    const int p   = (bid >> 3) * 256 + (int)threadIdx.x;
    if (p >= NBINS) return;

    float gx, gy, gz;
    decode_grid(p, b, gc, gx, gy, gz);
    {
        const size_t goff = (size_t)CUBES_ELEMS + ((size_t)b * NBINS + (size_t)p) * 3;
        out[goff + 0] = gx; out[goff + 1] = gy; out[goff + 2] = gz;
    }

    // Phase A: all projections + issue all 20 gathers
    Proj pr[N_VIEWS];
    uint4 q[N_VIEWS][4];
#pragma unroll
    for (int n = 0; n < N_VIEWS; ++n) {
        const int cb = n * B_ + b;
        pr[n] = project_one(cb, gx, gy, gz, R, T, f, ccam, trans, wh);
        const uint4* base = (const uint4*)tp + (size_t)cb * HW_;
        q[n][0] = base[pr[n].o00];
        q[n][1] = base[pr[n].o10];
        q[n][2] = base[pr[n].o01];
        q[n][3] = base[pr[n].o11];
    }

    // Phase B: accumulate
    float acc[CP_];
#pragma unroll
    for (int c = 0; c < CP_; ++c) acc[c] = 0.0f;
    float bndsum = 0.0f;
#pragma unroll
    for (int n = 0; n < N_VIEWS; ++n) {
        bndsum += pr[n].inb;
        acc_pixel(acc, q[n][0], pr[n].w00);
        acc_pixel(acc, q[n][1], pr[n].w10);
        acc_pixel(acc, q[n][2], pr[n].w01);
        acc_pixel(acc, q[n][3], pr[n].w11);
    }

    const float inv = 1.0f / (bndsum + 1e-6f);
    const size_t ob = (size_t)b * C_ * NBINS + (size_t)p;
#pragma unroll
    for (int c = 0; c < C_; ++c) {
        float r = acc[c] * inv;
        r = fmaxf(r, 0.0f);   // nan_to_num + clip low
        r = fminf(r, 1.0f);
        out[ob + (size_t)c * NBINS] = r;
    }
}

// ---------------------------------------------------------------------------
// Fallback: direct f32 gather (used only if ws too small). Exact math.
// ---------------------------------------------------------------------------
__global__ __launch_bounds__(256) void project_kernel_direct(
    const float* __restrict__ hm,
    const float* __restrict__ R, const float* __restrict__ T,
    const float* __restrict__ f, const float* __restrict__ ccam,
    const float* __restrict__ trans, const float* __restrict__ wh,
    const float* __restrict__ gc,
    float* __restrict__ out)
{
    const int p = blockIdx.x * blockDim.x + threadIdx.x;
    const int b = blockIdx.y;
    if (p >= NBINS) return;
    float gx, gy, gz;
    decode_grid(p, b, gc, gx, gy, gz);
    {
        const size_t goff = (size_t)CUBES_ELEMS + ((size_t)b * NBINS + (size_t)p) * 3;
        out[goff + 0] = gx; out[goff + 1] = gy; out[goff + 2] = gz;
    }
    float acc[C_];
#pragma unroll
    for (int c = 0; c < C_; ++c) acc[c] = 0.0f;
    float bndsum = 0.0f;
#pragma unroll
    for (int n = 0; n < N_VIEWS; ++n) {
        const int cb = n * B_ + b;
        Proj cr = project_one(cb, gx, gy, gz, R, T, f, ccam, trans, wh);
        bndsum += cr.inb;
        const float* img = hm + (size_t)cb * C_ * HW_;
#pragma unroll
        for (int c = 0; c < C_; ++c) {
            const float* ic = img + (size_t)c * HW_;
            acc[c] += cr.w00 * ic[cr.o00] + cr.w10 * ic[cr.o10]
                    + cr.w01 * ic[cr.o01] + cr.w11 * ic[cr.o11];
        }
    }
    const float inv = 1.0f / (bndsum + 1e-6f);
    const size_t ob = (size_t)b * C_ * NBINS + (size_t)p;
#pragma unroll
    for (int c = 0; c < C_; ++c) {
        float r = acc[c] * inv;
        r = fmaxf(r, 0.0f);
        r = fminf(r, 1.0f);
        out[ob + (size_t)c * NBINS] = r;
    }
}

extern "C" void kernel_launch(void* const* d_in, const int* in_sizes, int n_in,
                              void* d_out, int out_size, void* d_ws, size_t ws_size,
                              hipStream_t stream) {
    const float* hm    = (const float*)d_in[0];
    const float* R     = (const float*)d_in[1];
    const float* T     = (const float*)d_in[2];
    const float* f     = (const float*)d_in[3];
    const float* ccam  = (const float*)d_in[4];
    const float* trans = (const float*)d_in[5];
    const float* wh    = (const float*)d_in[6];
    const float* gc    = (const float*)d_in[7];
    float* out = (float*)d_out;

    const size_t ws_needed = (size_t)NB_ * HW_ * CP_; // 78.6 MB (fp8 bytes)

    if (ws_size >= ws_needed) {
        uint32_t* tp = (uint32_t*)d_ws;
        dim3 tgrid((HW_ + 255) / 256, NB_);   // 480 x 40
        transpose_fp8_kernel<<<tgrid, 256, 0, stream>>>(hm, tp);
        dim3 grid((NBINS / 256) * B_);        // 4000 flat, b = bid & 7
        project_kernel_fp8<<<grid, 256, 0, stream>>>(tp, R, T, f, ccam, trans, wh, gc, out);
    } else {
        dim3 grid(NBINS / 256, B_);
        project_kernel_direct<<<grid, 256, 0, stream>>>(hm, R, T, f, ccam, trans, wh, gc, out);
    }
}